// Round 13
// baseline (135.768 us; speedup 1.0000x reference)
//
#include <hip/hip_runtime.h>
#include <cstddef>

#define NN 256
#define DD 1024
#define CC 4
#define NT 512             // threads: each owns 2 rows x 4 cols
#define ROOT (NN - 1)

// Block mapping: s = bid & 63 (16-col strip), q = bid >> 6 (4-col quad).
// bid % 8 == s % 8: all 4 quads of a strip share an XCD -> L2 dedups the
// 4x line overfetch of row-major 16B reads.
// Meta bits: 0-12 dep | 13 fwd(child==last-finished) | 14 first | 15 last.

struct St {
  float4 p0, p1;  // P[dep][r2][j0..3], P[dep][r2+1][j0..3]
  float x0, x1;   // emb[node][r2], emb[node][r2+1] (last-child stages only)
};

__device__ __forceinline__ float4 relu4(float4 v) {
  float4 r;
  r.x = fmaxf(v.x, 0.f); r.y = fmaxf(v.y, 0.f);
  r.z = fmaxf(v.z, 0.f); r.w = fmaxf(v.w, 0.f);
  return r;
}
__device__ __forceinline__ float4 mul4(float4 a, float4 b) {
  float4 r; r.x = a.x*b.x; r.y = a.y*b.y; r.z = a.z*b.z; r.w = a.w*b.w; return r;
}
__device__ __forceinline__ float4 max4(float4 a, float4 b) {
  float4 r;
  r.x = fmaxf(a.x, b.x); r.y = fmaxf(a.y, b.y);
  r.z = fmaxf(a.z, b.z); r.w = fmaxf(a.w, b.w);
  return r;
}

__device__ __forceinline__ void ld_stage(St& S, int e, const float* __restrict__ par,
                                         const float* __restrict__ emb,
                                         const short* e_meta, const short* e_node,
                                         int j0, int r2) {
  const int meta = e_meta[e];
  const int dep = meta & 0x1FFF;
  const float* pb = par + (((size_t)dep) << 20) + (((size_t)r2) << 10) + j0;
  S.p0 = *(const float4*)(pb);
  S.p1 = *(const float4*)(pb + DD);
  if (meta & 0x8000) {
    const float2 xx = *(const float2*)(emb + (((size_t)e_node[e]) << 10) + r2);
    S.x0 = xx.x; S.x1 = xx.y;
  }
}

__device__ __forceinline__ void cmp_stage(const St& S, int e, float4& m0, float4& m1,
                                          float4& zreg, int& par,
                                          float (*z_loc)[4], float s_part[2][8][4],
                                          const short* e_child, const short* e_meta,
                                          const short* e_node, int tid) {
  const int meta = e_meta[e];
  float4 zc;
  if (meta & (1 << 13)) zc = zreg;                       // forward last-finished z
  else zc = *(const float4*)z_loc[e_child[e]];           // older nodes: LDS (safe)
  const float4 u = relu4(zc);
  if (meta & (1 << 14)) {  // first child of node
    m0 = mul4(S.p0, u);
    m1 = mul4(S.p1, u);
  } else {
    m0 = max4(m0, mul4(S.p0, u));
    m1 = max4(m1, mul4(S.p1, u));
  }
  if (meta & 0x8000) {  // last child: finish node
    float4 acc;
    acc.x = fmaf(S.x1, m1.x, S.x0 * m0.x);
    acc.y = fmaf(S.x1, m1.y, S.x0 * m0.y);
    acc.z = fmaf(S.x1, m1.z, S.x0 * m0.z);
    acc.w = fmaf(S.x1, m1.w, S.x0 * m0.w);
    // 64-lane butterfly (fixed order -> deterministic)
#pragma unroll
    for (int off = 1; off < 64; off <<= 1) {
      acc.x += __shfl_xor(acc.x, off, 64);
      acc.y += __shfl_xor(acc.y, off, 64);
      acc.z += __shfl_xor(acc.z, off, 64);
      acc.w += __shfl_xor(acc.w, off, 64);
    }
    if ((tid & 63) == 0) *(float4*)s_part[par][tid >> 6] = acc;
    // LDS-only barrier: ds ops drained, global prefetches STAY IN FLIGHT
    asm volatile("s_waitcnt lgkmcnt(0)" ::: "memory");
    __builtin_amdgcn_s_barrier();
    __builtin_amdgcn_sched_barrier(0);
    float4 s4 = {0.f, 0.f, 0.f, 0.f};
#pragma unroll
    for (int k = 0; k < 8; ++k) {  // all threads: redundant fixed-order sum
      s4.x += s_part[par][k][0];
      s4.y += s_part[par][k][1];
      s4.z += s_part[par][k][2];
      s4.w += s_part[par][k][3];
    }
    zreg = s4;
    if (tid == 0) *(float4*)z_loc[e_node[e]] = s4;  // ordered by NEXT finish barrier
    par ^= 1;
  }
}

__global__ __launch_bounds__(NT, 1) void dep_col_kernel(
    const float* __restrict__ emb, const float* __restrict__ par_,
    const int* __restrict__ cidx, const int* __restrict__ cdep,
    const unsigned char* __restrict__ cmask, float* __restrict__ out) {
  __shared__ float z_loc[NN][4];
  __shared__ short s_ci[NN][CC];
  __shared__ short s_cd[NN][CC];
  __shared__ short s_nc[NN];
  __shared__ int s_pfx[NN];
  __shared__ int s_mx[NN];
  __shared__ unsigned char s_reach[NN];
  __shared__ short s_e_child[NN * CC];
  __shared__ short s_e_meta[NN * CC];
  __shared__ short s_e_node[NN * CC];
  __shared__ int s_NE;
  __shared__ int s_flag;
  __shared__ float s_part[2][8][4];

  const int tid = threadIdx.x;
  const int strip = blockIdx.x & 63;
  const int quad = blockIdx.x >> 6;
  const int j0 = strip * 16 + quad * 4;
  const int r2 = tid << 1;

  // ---- Phase 1: schedule build (LDS only, identical in every block) ----
  if (tid == 0)
    s_flag = (cmask[1021] == 1 && cmask[1022] == 1 && cmask[1023] == 1);
  __syncthreads();
  const bool m_u8 = (s_flag != 0);
  const int* m32 = (const int*)cmask;
  if (tid < NN) {
    int nc = 0;
#pragma unroll
    for (int c = 0; c < CC; ++c) {
      bool mk = m_u8 ? (cmask[tid * CC + c] != 0) : (m32[tid * CC + c] != 0);
      if (mk) {
        s_ci[tid][nc] = (short)cidx[tid * CC + c];
        s_cd[tid][nc] = (short)cdep[tid * CC + c];
        ++nc;
      }
    }
    s_nc[tid] = (short)nc;
    s_reach[tid] = (tid == ROOT) ? 1 : 0;
  }
  __syncthreads();

  // Reachability fixpoint (root downward; <= depth passes)
  for (int it = 0; it < NN + 2; ++it) {
    if (tid == 0) s_flag = 0;
    __syncthreads();
    if (tid < NN && s_reach[tid] && s_nc[tid] > 0) {
      for (int c = 0; c < s_nc[tid]; ++c) {
        const int ch = s_ci[tid][c];
        if (!s_reach[ch]) { s_reach[ch] = 1; s_flag = 1; }
      }
    }
    __syncthreads();
    const int chg = s_flag;
    __syncthreads();
    if (!chg) break;
  }

  const int activ = (tid < NN && s_reach[tid] && s_nc[tid] > 0) ? 1 : 0;
  // Sum-scan of child counts + max-scan of internal-node indices (prev finder)
  const int wgt = activ ? (int)s_nc[tid] : 0;
  if (tid < NN) {
    s_pfx[tid] = wgt;
    s_mx[tid] = activ ? tid : -1;
  }
  __syncthreads();
  for (int off = 1; off < NN; off <<= 1) {
    int v = 0, w = -1;
    if (tid < NN && tid >= off) { v = s_pfx[tid - off]; w = s_mx[tid - off]; }
    __syncthreads();
    if (tid < NN) {
      s_pfx[tid] += v;
      s_mx[tid] = max(s_mx[tid], w);
    }
    __syncthreads();
  }
  // Emit child-stream entries (ascending node index = topological order)
  if (activ) {
    const int prv = (tid > 0) ? s_mx[tid - 1] : -1;  // last node finished before us
    const int st = s_pfx[tid] - wgt;
    for (int c = 0; c < wgt; ++c) {
      const int ch = s_ci[tid][c];
      s_e_child[st + c] = (short)ch;
      int meta = (int)s_cd[tid][c];
      if (ch == prv) meta |= 1 << 13;
      if (c == 0) meta |= 1 << 14;
      if (c == wgt - 1) meta |= 1 << 15;
      s_e_meta[st + c] = (short)meta;
      s_e_node[st + c] = (short)tid;
    }
  }
  if (tid == NN - 1) s_NE = s_pfx[NN - 1];

  // Init z_loc from embeddings (leaf z = x; internal overwritten in topo order)
  if (tid < NN) {
    const float4 e = *(const float4*)(emb + (((size_t)tid) << 10) + j0);
    *(float4*)z_loc[tid] = e;
  }
  __syncthreads();
  const int NE = s_NE;

  // ---- Phase 2: 6-deep pipelined serial walk; lgkm-only finish barriers ----
  St A, B, C, D, E, F;
  float4 m0, m1;
  float4 zreg = {0.f, 0.f, 0.f, 0.f};
  int par = 0;
  if (NE > 0) ld_stage(A, 0, par_, emb, s_e_meta, s_e_node, j0, r2);
  if (NE > 1) ld_stage(B, 1, par_, emb, s_e_meta, s_e_node, j0, r2);
  if (NE > 2) ld_stage(C, 2, par_, emb, s_e_meta, s_e_node, j0, r2);
  if (NE > 3) ld_stage(D, 3, par_, emb, s_e_meta, s_e_node, j0, r2);
  if (NE > 4) ld_stage(E, 4, par_, emb, s_e_meta, s_e_node, j0, r2);
  int e = 0;
  while (e < NE) {
    if (e + 5 < NE) ld_stage(F, e + 5, par_, emb, s_e_meta, s_e_node, j0, r2);
    cmp_stage(A, e, m0, m1, zreg, par, z_loc, s_part, s_e_child, s_e_meta, s_e_node, tid);
    if (++e >= NE) break;
    if (e + 5 < NE) ld_stage(A, e + 5, par_, emb, s_e_meta, s_e_node, j0, r2);
    cmp_stage(B, e, m0, m1, zreg, par, z_loc, s_part, s_e_child, s_e_meta, s_e_node, tid);
    if (++e >= NE) break;
    if (e + 5 < NE) ld_stage(B, e + 5, par_, emb, s_e_meta, s_e_node, j0, r2);
    cmp_stage(C, e, m0, m1, zreg, par, z_loc, s_part, s_e_child, s_e_meta, s_e_node, tid);
    if (++e >= NE) break;
    if (e + 5 < NE) ld_stage(C, e + 5, par_, emb, s_e_meta, s_e_node, j0, r2);
    cmp_stage(D, e, m0, m1, zreg, par, z_loc, s_part, s_e_child, s_e_meta, s_e_node, tid);
    if (++e >= NE) break;
    if (e + 5 < NE) ld_stage(D, e + 5, par_, emb, s_e_meta, s_e_node, j0, r2);
    cmp_stage(E, e, m0, m1, zreg, par, z_loc, s_part, s_e_child, s_e_meta, s_e_node, tid);
    if (++e >= NE) break;
    if (e + 5 < NE) ld_stage(E, e + 5, par_, emb, s_e_meta, s_e_node, j0, r2);
    cmp_stage(F, e, m0, m1, zreg, par, z_loc, s_part, s_e_child, s_e_meta, s_e_node, tid);
    ++e;
  }

  // ---- Output: last finished node is ROOT; zreg holds its z in all threads ----
  if (tid == 0) *(float4*)(out + j0) = zreg;
}

extern "C" void kernel_launch(void* const* d_in, const int* in_sizes, int n_in,
                              void* d_out, int out_size, void* d_ws, size_t ws_size,
                              hipStream_t stream) {
  const float* emb = (const float*)d_in[0];
  const float* par = (const float*)d_in[1];
  const int* cidx = (const int*)d_in[2];
  const int* cdep = (const int*)d_in[3];
  const unsigned char* cmask = (const unsigned char*)d_in[4];
  float* out = (float*)d_out;

  hipLaunchKernelGGL(dep_col_kernel, dim3(256), dim3(NT), 0, stream, emb, par,
                     cidx, cdep, cmask, out);
}